// Round 1
// baseline (257.003 us; speedup 1.0000x reference)
//
#include <hip/hip_runtime.h>
#include <float.h>

// Problem constants (from reference): x [64,64,32,32] f32, weight [1024,64] f32
#define NLAT   65536   // 64*32*32 latents
#define KCODES 1024
#define DIM    64
#define HW     1024    // 32*32 spatial per image
#define KSPLIT 4       // threads per latent, splitting K
#define LPB    64      // latents per block (block = LPB*KSPLIT = 256 threads)
#define CHUNK  128     // codes staged in LDS per iter (32 per K-quarter)
#define ITERS  8       // 256 codes/quarter / 32 per iter

// Kernel 1: wn[k] = 0.5 * sum_d w[k][d]^2  (argmin(0.5*||w||^2 - x.w) == ref argmin)
__global__ void vq_wnorm(const float* __restrict__ w, float* __restrict__ wn) {
    int k = blockIdx.x * blockDim.x + threadIdx.x;
    if (k < KCODES) {
        const float4* w4 = (const float4*)(w + (size_t)k * DIM);
        float s = 0.f;
        #pragma unroll
        for (int j = 0; j < DIM / 4; ++j) {
            float4 v = w4[j];
            s += v.x * v.x + v.y * v.y + v.z * v.z + v.w * v.w;
        }
        wn[k] = 0.5f * s;
    }
}

// Kernel 2: per-latent argmin over K, then gather weight[best] to out.
// block=256: 64 latents x 4-way K split; 4 blocks/CU (LDS ~35KB), 16 waves/CU.
__global__ __launch_bounds__(256, 4)
void vq_main(const float* __restrict__ x, const float* __restrict__ w,
             const float* __restrict__ wn, float* __restrict__ out) {
    __shared__ float sw[CHUNK][DIM];     // 32 KB staged codes
    __shared__ float swn[CHUNK];
    __shared__ float rs[KSPLIT][LPB];
    __shared__ int   ri[KSPLIT][LPB];
    __shared__ int   bfin[LPB];

    const int tid  = threadIdx.x;
    const int llat = tid & 63;   // latent within block
    const int kq   = tid >> 6;   // K-quarter 0..3
    const int n    = blockIdx.x * LPB + llat;
    const int b    = n >> 10;    // image index
    const int hw   = n & 1023;   // spatial index
    const float* xp = x + (size_t)b * (DIM * HW) + hw;

    // Latent row in registers; lanes 0..63 of a wave have consecutive hw -> coalesced per channel.
    float lat[DIM];
    #pragma unroll
    for (int c = 0; c < DIM; ++c) lat[c] = xp[c * HW];

    float best = FLT_MAX;
    int   bidx = 0;

    for (int it = 0; it < ITERS; ++it) {
        __syncthreads();
        // Stage 128 code rows: LDS row (q*32+j) <- global code (q*256 + it*32 + j)
        #pragma unroll
        for (int r = 0; r < 8; ++r) {
            int idx4 = r * 256 + tid;        // float4 index 0..2047
            int row  = idx4 >> 4;            // 16 float4 per 64-float row
            int col  = (idx4 & 15) << 2;
            int q = row >> 5, j = row & 31;
            int gk = q * 256 + it * 32 + j;
            *(float4*)&sw[row][col] = *(const float4*)&w[(size_t)gk * DIM + col];
        }
        if (tid < CHUNK) {
            int q = tid >> 5, j = tid & 31;
            swn[tid] = wn[q * 256 + it * 32 + j];
        }
        __syncthreads();

        const int rowbase = kq * 32;
        const int kbase   = kq * 256 + it * 32;
        #pragma unroll 2
        for (int j = 0; j < 32; ++j) {
            const float4* wr = (const float4*)sw[rowbase + j];  // broadcast across wave
            float a0 = 0.f, a1 = 0.f, a2 = 0.f, a3 = 0.f;       // 4 indep FMA chains
            #pragma unroll
            for (int dd = 0; dd < DIM / 4; ++dd) {
                float4 v = wr[dd];
                a0 += lat[4 * dd + 0] * v.x;
                a1 += lat[4 * dd + 1] * v.y;
                a2 += lat[4 * dd + 2] * v.z;
                a3 += lat[4 * dd + 3] * v.w;
            }
            float score = swn[rowbase + j] - ((a0 + a1) + (a2 + a3));
            bool lt = score < best;          // strict < : first-occurrence tie-break
            best = lt ? score : best;
            bidx = lt ? (kbase + j) : bidx;
        }
    }

    rs[kq][llat] = best;
    ri[kq][llat] = bidx;
    __syncthreads();
    if (tid < LPB) {
        float bb = rs[0][tid];
        int   bi = ri[0][tid];
        #pragma unroll
        for (int q = 1; q < KSPLIT; ++q) {   // ascending q => lower k wins ties
            float s = rs[q][tid];
            bool lt = s < bb;
            bb = lt ? s : bb;
            bi = lt ? ri[q][tid] : bi;
        }
        bfin[tid] = bi;
    }
    __syncthreads();

    // Cooperative coalesced gather: out[n][:] = weight[bfin[lat]][:]
    float* outp = out + (size_t)blockIdx.x * (LPB * DIM);
    #pragma unroll
    for (int r = 0; r < 4; ++r) {
        int idx4 = r * 256 + tid;            // 0..1023 float4s = 64x64 floats
        int row  = idx4 >> 4;
        int col  = (idx4 & 15) << 2;
        int code = bfin[row];
        *(float4*)&outp[idx4 * 4] = *(const float4*)&w[(size_t)code * DIM + col];
    }
}

extern "C" void kernel_launch(void* const* d_in, const int* in_sizes, int n_in,
                              void* d_out, int out_size, void* d_ws, size_t ws_size,
                              hipStream_t stream) {
    const float* x = (const float*)d_in[0];   // [64,64,32,32]
    const float* w = (const float*)d_in[1];   // [1024,64]
    float* out = (float*)d_out;               // [65536,64]
    float* wn  = (float*)d_ws;                // 1024 floats scratch

    vq_wnorm<<<KCODES / 256, 256, 0, stream>>>(w, wn);
    vq_main<<<NLAT / LPB, 256, 0, stream>>>(x, w, wn, out);
}

// Round 2
// 184.176 us; speedup vs baseline: 1.3954x; 1.3954x over previous
//
#include <hip/hip_runtime.h>
#include <float.h>

// Problem: x [64,64,32,32] f32, weight [1024,64] f32
// out[n] = weight[argmin_k ||x_n - w_k||^2]  (argmin == argmin of 0.5||w||^2 - x.w)
#define NLAT   65536
#define KCODES 1024
#define DIM    64
#define HW     1024
#define LPB    128    // latents per block
#define CPK    128    // codes per chunk
#define NCHUNK 8      // 1024/128

// ---------------------------------------------------------------------------
// Prep: wt[d][k] = w[k][d] (transposed codebook, 256 KB) ; wn[k] = 0.5*||w_k||^2
// grid 16 x 256, each block transposes a 64-code tile.
__global__ void vq_prep(const float* __restrict__ w, float* __restrict__ wt,
                        float* __restrict__ wn) {
    __shared__ float tile[64][65];            // +1 pad: conflict-free column reads
    const int k0 = blockIdx.x * 64;
    const int tid = threadIdx.x;
    #pragma unroll
    for (int r = 0; r < 4; ++r) {             // load 64x64 floats, coalesced
        int i4 = r * 256 + tid;
        int row = i4 >> 4, col = (i4 & 15) << 2;
        float4 v = *(const float4*)&w[(size_t)(k0 + row) * DIM + col];
        tile[row][col] = v.x; tile[row][col + 1] = v.y;
        tile[row][col + 2] = v.z; tile[row][col + 3] = v.w;
    }
    __syncthreads();
    #pragma unroll
    for (int r = 0; r < 16; ++r) {            // write wt[d][k0+j], coalesced
        int idx = r * 256 + tid;
        int d = idx >> 6, j = idx & 63;
        wt[d * KCODES + k0 + j] = tile[j][d];
    }
    if (tid < 64) {
        float s = 0.f;
        #pragma unroll
        for (int d = 0; d < DIM; ++d) { float v = tile[tid][d]; s += v * v; }
        wn[k0 + tid] = 0.5f * s;
    }
}

// ---------------------------------------------------------------------------
// Main: block = 256 threads, tile = 128 latents x 128-code chunks (8 chunks).
// Thread micro-tile: 8 latents x 8 codes (64 fp32 accumulators).
// Per d-step: 4 ds_read_b128 feed 64 FMAs -> FMA-bound (1 read / 16 MACs).
__global__ __launch_bounds__(256, 2)
void vq_main(const float* __restrict__ x, const float* __restrict__ w,
             const float* __restrict__ wt, const float* __restrict__ wn,
             float* __restrict__ out) {
    __shared__ float sx_t[DIM][LPB];          // 32 KB latents, d-major
    __shared__ float sc_t[DIM][CPK];          // 32 KB code chunk, d-major
    __shared__ float swn_s[CPK];
    __shared__ int   bfin[LPB];

    const int tid  = threadIdx.x;
    const int wave = tid >> 6, lane = tid & 63;
    const int lrow = lane >> 3, lcol = lane & 7;
    const int LR = (wave >> 1) * 8 + lrow;    // latent group 0..15
    const int CC = (wave & 1) * 8 + lcol;     // code group 0..15
    const int latbase  = LR * 8;
    const int codebase = CC * 8;

    const int blk = blockIdx.x;
    const int b     = blk >> 3;               // image (128 | 1024, so uniform)
    const int hwoff = (blk & 7) * LPB;

    // Stage latents: x[b][c][hwoff + 0..127] -> sx_t[c][0..127] (coalesced)
    {
        const int c_idx = tid >> 5, f4 = (tid & 31) << 2;
        const float* xb = x + (size_t)b * (DIM * HW) + hwoff;
        #pragma unroll
        for (int r = 0; r < 8; ++r) {
            int c = r * 8 + c_idx;
            *(float4*)&sx_t[c][f4] = *(const float4*)&xb[c * HW + f4];
        }
    }

    float best[8], bidx_f; int bidx[8];
    #pragma unroll
    for (int i = 0; i < 8; ++i) { best[i] = FLT_MAX; bidx[i] = 0; }
    (void)bidx_f;

    for (int ch = 0; ch < NCHUNK; ++ch) {
        const int kbase = ch * CPK;
        __syncthreads();
        // Stage code chunk: wt[d][kbase + 0..127] -> sc_t[d][0..127] (coalesced)
        {
            const int d_idx = tid >> 5, f4 = (tid & 31) << 2;
            #pragma unroll
            for (int r = 0; r < 8; ++r) {
                int d = r * 8 + d_idx;
                *(float4*)&sc_t[d][f4] = *(const float4*)&wt[d * KCODES + kbase + f4];
            }
            if (tid < 32)
                *(float4*)&swn_s[tid << 2] = *(const float4*)&wn[kbase + (tid << 2)];
        }
        __syncthreads();

        float acc[8][8];
        #pragma unroll
        for (int i = 0; i < 8; ++i)
            #pragma unroll
            for (int j = 0; j < 8; ++j) acc[i][j] = 0.f;

        #pragma unroll 4
        for (int d = 0; d < DIM; ++d) {
            float4 la0 = *(const float4*)&sx_t[d][latbase];
            float4 la1 = *(const float4*)&sx_t[d][latbase + 4];
            float4 co0 = *(const float4*)&sc_t[d][codebase];
            float4 co1 = *(const float4*)&sc_t[d][codebase + 4];
            float la[8] = {la0.x, la0.y, la0.z, la0.w, la1.x, la1.y, la1.z, la1.w};
            float co[8] = {co0.x, co0.y, co0.z, co0.w, co1.x, co1.y, co1.z, co1.w};
            #pragma unroll
            for (int i = 0; i < 8; ++i)
                #pragma unroll
                for (int j = 0; j < 8; ++j)
                    acc[i][j] += la[i] * co[j];
        }

        // Fold into running argmin (j ascending + chunk ascending = k ascending;
        // strict < keeps first occurrence)
        #pragma unroll
        for (int j = 0; j < 8; ++j) {
            float sn = swn_s[codebase + j];
            int   k  = kbase + codebase + j;
            #pragma unroll
            for (int i = 0; i < 8; ++i) {
                float s = sn - acc[i][j];
                bool lt = s < best[i];
                best[i] = lt ? s : best[i];
                bidx[i] = lt ? k : bidx[i];
            }
        }
    }

    // Cross-thread reduction over the 16 code groups (alias dead tile buffers)
    __syncthreads();
    float* rs = (float*)sc_t;                 // [16][128]
    int*   ri = (int*)sx_t;                   // [16][128]
    #pragma unroll
    for (int i = 0; i < 8; ++i) {
        rs[CC * LPB + latbase + i] = best[i];
        ri[CC * LPB + latbase + i] = bidx[i];
    }
    __syncthreads();
    if (tid < LPB) {
        float bb = rs[tid]; int bi = ri[tid];
        #pragma unroll
        for (int q = 1; q < 16; ++q) {
            float s = rs[q * LPB + tid]; int k2 = ri[q * LPB + tid];
            if (s < bb || (s == bb && k2 < bi)) { bb = s; bi = k2; }
        }
        bfin[tid] = bi;
    }
    __syncthreads();

    // Gather: out[n][:] = w[bfin[n - n0]][:]  (coalesced float4 writes)
    float* outp = out + (size_t)blk * (LPB * DIM);
    #pragma unroll
    for (int r = 0; r < 8; ++r) {
        int idx4 = r * 256 + tid;             // 2048 float4 = 128x64 floats
        int row = idx4 >> 4, col = (idx4 & 15) << 2;
        int code = bfin[row];
        *(float4*)&outp[idx4 << 2] = *(const float4*)&w[(size_t)code * DIM + col];
    }
}

extern "C" void kernel_launch(void* const* d_in, const int* in_sizes, int n_in,
                              void* d_out, int out_size, void* d_ws, size_t ws_size,
                              hipStream_t stream) {
    const float* x = (const float*)d_in[0];   // [64,64,32,32]
    const float* w = (const float*)d_in[1];   // [1024,64]
    float* out = (float*)d_out;               // [65536,64]
    float* wt  = (float*)d_ws;                // [64][1024] transposed codebook
    float* wn  = wt + DIM * KCODES;           // [1024] 0.5*||w||^2

    vq_prep<<<16, 256, 0, stream>>>(w, wt, wn);
    vq_main<<<NLAT / LPB, 256, 0, stream>>>(x, w, wt, wn, out);
}

// Round 3
// 146.560 us; speedup vs baseline: 1.7536x; 1.2567x over previous
//
#include <hip/hip_runtime.h>
#include <float.h>

// VectorQuantizer: x [64,64,32,32] f32, weight [1024,64] f32
// out[n] = weight[argmin_k ||x_n - w_k||^2]
// Strategy: split fp32 -> bf16 hi+lo; score = 0.5||w||^2 - x.w via K=256
// expanded bf16 MFMA (4 cross terms, fp32 accum). Error <= ~2.4e-4.
// Latents with top-2 margin < EPS get exact fp32 rescore (rescue kernel).
#define NLAT   65536
#define KCODES 1024
#define DIM    64
#define HW     1024
#define LPB    128          // latents per block
#define CPK    128          // codes per chunk
#define NCHUNK 8
#define XROW   136          // padded LDS row: 128 bf16 + 8 pad (272 B, 17x16B)
#define EPS    2.0e-3f
#define RESCUE_CAP 4096

typedef float f32x4 __attribute__((ext_vector_type(4)));
typedef short short8 __attribute__((ext_vector_type(8)));

static __device__ __forceinline__ unsigned short f2bf(float f) {
    unsigned int u = __float_as_uint(f);
    unsigned int r = (u + 0x7fffu + ((u >> 16) & 1u)) >> 16;   // RNE
    return (unsigned short)r;
}
static __device__ __forceinline__ float bf2f(unsigned short h) {
    return __uint_as_float(((unsigned int)h) << 16);
}

// ---------------------------------------------------------------------------
// Prep: WEg[k][0..63]=hi(w[k]), [64..127]=lo(w[k]); wn[k]=0.5*||w_k||^2; ctr=0
__global__ void vq_prep(const float* __restrict__ w, unsigned short* __restrict__ WEg,
                        float* __restrict__ wn, int* __restrict__ ctr) {
    int k = blockIdx.x * blockDim.x + threadIdx.x;   // 8 x 128 = 1024
    if (k == 0) ctr[0] = 0;
    if (k >= KCODES) return;
    float s = 0.f;
    #pragma unroll
    for (int d = 0; d < DIM; ++d) {
        float v = w[(size_t)k * DIM + d];
        unsigned short h = f2bf(v);
        float hf = bf2f(h);
        unsigned short l = f2bf(v - hf);
        WEg[(size_t)k * 128 + d]      = h;
        WEg[(size_t)k * 128 + 64 + d] = l;
        s += v * v;
    }
    wn[k] = 0.5f * s;
}

// ---------------------------------------------------------------------------
// Main: 512 blocks x 256 thr (4 waves). Block = 128 latents x all 1024 codes.
// Wave tile: 64 lats x 64 codes per chunk (4x4 mfma 16x16 tiles, 8 k-steps).
// A-frags (latents, K=256 expanded) live in registers across all chunks.
__global__ __launch_bounds__(256, 2)
void vq_main(const float* __restrict__ x, const float* __restrict__ w,
             const unsigned short* __restrict__ WEg, const float* __restrict__ wn,
             float* __restrict__ out, int* __restrict__ ctr, int* __restrict__ list) {
    __shared__ __align__(16) char smem[70656];
    unsigned short* XE  = (unsigned short*)smem;            // [128][136] bf16
    unsigned short* WEs = (unsigned short*)(smem + 34816);  // [128][136] bf16
    float* swn = (float*)(smem + 69632);                    // [128]
    int*   bfin = (int*)(smem + 70144);                     // [128]
    // post-K aliases (XE dead after A-frag load; WEs dead after last chunk)
    float* red_b1 = (float*)smem;                           // [32][129]
    int*   red_i1 = (int*)(smem + 16512);                   // [32][129]
    float* red_b2 = (float*)(smem + 34816);                 // [32][129]

    const int tid  = threadIdx.x;
    const int wave = tid >> 6, lane = tid & 63;
    const int r16  = lane & 15, quad = lane >> 4;
    const int LH = wave & 1;        // latent half (64 lats)
    const int CH = wave >> 1;       // code half within chunk (64 codes)

    const int blk = blockIdx.x;
    const int b   = blk >> 3;                 // 128 latents | 1024 spatial
    const int hw0 = (blk & 7) * LPB;

    // ---- Phase 0: convert x tile to bf16 hi/lo into XE[lat][0..127] ----
    {
        const int lat  = tid & 127;
        const int half = tid >> 7;            // 32-channel half
        const float* xb = x + (size_t)b * (DIM * HW) + hw0 + lat;
        #pragma unroll 8
        for (int c = 0; c < 32; ++c) {
            int ch = half * 32 + c;
            float v = xb[ch * HW];            // lanes: consecutive lat -> coalesced
            unsigned short h = f2bf(v);
            unsigned short l = f2bf(v - bf2f(h));
            XE[lat * XROW + ch]      = h;
            XE[lat * XROW + 64 + ch] = l;
        }
    }
    __syncthreads();

    // ---- Load A-frags to registers: 4 lat-tiles x 4 spans (hi0,hi1,lo0,lo1)
    short8 areg[4][4];
    #pragma unroll
    for (int lt = 0; lt < 4; ++lt)
        #pragma unroll
        for (int p = 0; p < 4; ++p)
            areg[lt][p] = *(const short8*)&XE[(LH * 64 + lt * 16 + r16) * XROW + p * 32 + quad * 8];

    float b1[16], b2[16]; int i1[16];
    #pragma unroll
    for (int sl = 0; sl < 16; ++sl) { b1[sl] = FLT_MAX; b2[sl] = FLT_MAX; i1[sl] = 0; }

    for (int ch = 0; ch < NCHUNK; ++ch) {
        __syncthreads();
        // Stage WE chunk: 128 codes x 256 B -> WEs rows (272 B padded)
        {
            const unsigned short* src = WEg + (size_t)(ch * CPK) * 128;
            #pragma unroll
            for (int r = 0; r < 8; ++r) {
                int idx = r * 256 + tid;          // 2048 x 16B
                int row = idx >> 4, seg = idx & 15;
                *(int4*)&WEs[row * XROW + seg * 8] = *(const int4*)&src[row * 128 + seg * 8];
            }
            if (tid < 32) *(float4*)&swn[tid * 4] = *(const float4*)&wn[ch * CPK + tid * 4];
        }
        __syncthreads();

        f32x4 acc[4][4];
        #pragma unroll
        for (int lt = 0; lt < 4; ++lt)
            #pragma unroll
            for (int ct = 0; ct < 4; ++ct) acc[lt][ct] = (f32x4)0.f;

        // K=256 expanded: s-steps; X pattern [hi,hi,lo,lo], W pattern [hi,lo,hi,lo]
        #pragma unroll
        for (int s = 0; s < 8; ++s) {
            const int ob = ((s >> 1) & 1) * 64 + (s & 1) * 32 + quad * 8;
            const int ai = (s >> 2) * 2 + (s & 1);
            short8 bf[4];
            #pragma unroll
            for (int ct = 0; ct < 4; ++ct)
                bf[ct] = *(const short8*)&WEs[(CH * 64 + ct * 16 + r16) * XROW + ob];
            #pragma unroll
            for (int lt = 0; lt < 4; ++lt)
                #pragma unroll
                for (int ct = 0; ct < 4; ++ct)
                    acc[lt][ct] = __builtin_amdgcn_mfma_f32_16x16x32_bf16(
                        areg[lt][ai], bf[ct], acc[lt][ct], 0, 0, 0);
        }

        // Fold scores: score = wn - dot ; k ascending (ct asc, chunk asc)
        #pragma unroll
        for (int ct = 0; ct < 4; ++ct) {
            float wnv = swn[CH * 64 + ct * 16 + r16];
            int   kk  = ch * CPK + CH * 64 + ct * 16 + r16;
            #pragma unroll
            for (int lt = 0; lt < 4; ++lt) {
                #pragma unroll
                for (int r = 0; r < 4; ++r) {
                    int sl = lt * 4 + r;
                    float sc = wnv - acc[lt][ct][r];
                    bool ltb = sc < b1[sl];
                    float loser = ltb ? b1[sl] : sc;
                    b1[sl] = ltb ? sc : b1[sl];
                    i1[sl] = ltb ? kk : i1[sl];
                    b2[sl] = fminf(b2[sl], loser);
                }
            }
        }
    }

    // ---- Cross-lane/wave reduction via LDS (32 contributors per latent) ----
    __syncthreads();   // WEs/XE now dead
    {
        const int cid = CH * 16 + r16;
        #pragma unroll
        for (int lt = 0; lt < 4; ++lt)
            #pragma unroll
            for (int r = 0; r < 4; ++r) {
                int sl = lt * 4 + r;
                int lat = LH * 64 + lt * 16 + quad * 4 + r;
                red_b1[cid * 129 + lat] = b1[sl];
                red_i1[cid * 129 + lat] = i1[sl];
                red_b2[cid * 129 + lat] = b2[sl];
            }
    }
    __syncthreads();
    if (tid < LPB) {
        float B1 = red_b1[tid]; int I1 = red_i1[tid]; float B2 = red_b2[tid];
        #pragma unroll 4
        for (int cid = 1; cid < 32; ++cid) {
            float c1 = red_b1[cid * 129 + tid];
            int   ci = red_i1[cid * 129 + tid];
            float c2 = red_b2[cid * 129 + tid];
            if (c1 < B1 || (c1 == B1 && ci < I1)) {
                B2 = fminf(B1, c2); B1 = c1; I1 = ci;
            } else {
                B2 = fminf(B2, c1);
            }
        }
        bfin[tid] = I1;
        if (B2 - B1 < EPS) {                 // ambiguous under bf16 error: rescue
            int pos = atomicAdd(ctr, 1);
            if (pos < RESCUE_CAP) list[pos] = blk * LPB + tid;
        }
    }
    __syncthreads();

    // ---- Gather: out[n][:] = w[bfin][:]  (coalesced float4) ----
    float* outp = out + (size_t)blk * (LPB * DIM);
    #pragma unroll
    for (int r = 0; r < 8; ++r) {
        int idx = r * 256 + tid;             // 2048 float4
        int row = idx >> 4, seg = idx & 15;
        int code = bfin[row];
        *(float4*)&outp[idx * 4] = *(const float4*)&w[(size_t)code * DIM + seg * 4];
    }
}

// ---------------------------------------------------------------------------
// Rescue: exact fp32 full-K rescore for ambiguous latents (expected ~dozens).
__global__ void vq_rescue(const float* __restrict__ x, const float* __restrict__ w,
                          const float* __restrict__ wn, float* __restrict__ out,
                          const int* __restrict__ ctr, const int* __restrict__ list) {
    __shared__ float xs[DIM];
    __shared__ float bred[256];
    __shared__ int   ired[256];
    const int tid = threadIdx.x;
    int cnt = ctr[0]; if (cnt > RESCUE_CAP) cnt = RESCUE_CAP;
    for (int e = blockIdx.x; e < cnt; e += gridDim.x) {
        int n = list[e];
        int b = n >> 10, hw = n & 1023;
        if (tid < DIM) xs[tid] = x[(size_t)b * (DIM * HW) + tid * HW + hw];
        __syncthreads();
        float bb = FLT_MAX; int bi = 0;
        #pragma unroll
        for (int j = 0; j < 4; ++j) {
            int k = tid * 4 + j;
            float dot = 0.f;
            #pragma unroll
            for (int d = 0; d < DIM; ++d) dot += xs[d] * w[(size_t)k * DIM + d];
            float s = wn[k] - dot;
            if (s < bb) { bb = s; bi = k; }
        }
        bred[tid] = bb; ired[tid] = bi;
        __syncthreads();
        for (int off = 128; off > 0; off >>= 1) {
            if (tid < off) {
                float s2 = bred[tid + off]; int k2 = ired[tid + off];
                if (s2 < bred[tid] || (s2 == bred[tid] && k2 < ired[tid])) {
                    bred[tid] = s2; ired[tid] = k2;
                }
            }
            __syncthreads();
        }
        int kw = ired[0];
        if (tid < DIM) out[(size_t)n * DIM + tid] = w[(size_t)kw * DIM + tid];
        __syncthreads();
    }
}

extern "C" void kernel_launch(void* const* d_in, const int* in_sizes, int n_in,
                              void* d_out, int out_size, void* d_ws, size_t ws_size,
                              hipStream_t stream) {
    const float* x = (const float*)d_in[0];
    const float* w = (const float*)d_in[1];
    float* out = (float*)d_out;
    // ws layout
    unsigned short* WEg = (unsigned short*)d_ws;                  // 262144 B
    float* wn = (float*)((char*)d_ws + 262144);                   // 4096 B
    int*   ctr = (int*)((char*)d_ws + 266240);                    // 16 B
    int*   list = (int*)((char*)d_ws + 266256);                   // 16384 B

    vq_prep<<<8, 128, 0, stream>>>(w, WEg, wn, ctr);
    vq_main<<<NLAT / LPB, 256, 0, stream>>>(x, w, WEg, wn, out, ctr, list);
    vq_rescue<<<64, 256, 0, stream>>>(x, w, wn, out, ctr, list);
}

// Round 4
// 143.258 us; speedup vs baseline: 1.7940x; 1.0231x over previous
//
#include <hip/hip_runtime.h>
#include <float.h>

// VectorQuantizer: x [64,64,32,32] f32, weight [1024,64] f32
// out[n] = weight[argmin_k ||x_n - w_k||^2]
// score = 0.5||w||^2 - x.w via split-bf16 MFMA, K=192 (hi.hi + lo_x.hi_w +
// hi_x.lo_w; lo.lo dropped, ~1e-5 << EPS). Ambiguous margins -> exact rescue.
#define NLAT   65536
#define KCODES 1024
#define DIM    64
#define HW     1024
#define LPB    128
#define CPK    128
#define NCHUNK 8
#define XROW   136          // XE padded row (shorts)
#define EPS    2.0e-3f
#define RESCUE_CAP 4096

typedef float f32x4 __attribute__((ext_vector_type(4)));
typedef short short8 __attribute__((ext_vector_type(8)));

static __device__ __forceinline__ unsigned short f2bf(float f) {
    unsigned int u = __float_as_uint(f);
    return (unsigned short)((u + 0x7fffu + ((u >> 16) & 1u)) >> 16);   // RNE
}
static __device__ __forceinline__ float bf2f(unsigned short h) {
    return __uint_as_float(((unsigned int)h) << 16);
}
static __device__ __forceinline__ void async_cp16(const void* g, void* l) {
    __builtin_amdgcn_global_load_lds(
        (const __attribute__((address_space(1))) unsigned int*)g,
        (__attribute__((address_space(3))) unsigned int*)l, 16, 0, 0);
}

// ---------------------------------------------------------------------------
// Prep: WEg[k] = 256 B row of 16 swizzled 16B segs. Logical seg L: L<8 ->
// hi(d=8L..8L+7), L>=8 -> lo. Physical position = L ^ (k & 15)  (bank swizzle,
// baked into global so chunk staging is a byte-linear DMA copy).
__global__ void vq_prep(const float* __restrict__ w, unsigned short* __restrict__ WEg,
                        float* __restrict__ wn, int* __restrict__ ctr) {
    int k = blockIdx.x * blockDim.x + threadIdx.x;   // 4 x 256 = 1024
    if (k == 0) ctr[0] = 0;
    if (k >= KCODES) return;
    float s = 0.f;
    #pragma unroll
    for (int d = 0; d < DIM; ++d) { float v = w[(size_t)k * DIM + d]; s += v * v; }
    wn[k] = 0.5f * s;
    unsigned short* row = WEg + (size_t)k * 128;
    #pragma unroll
    for (int L = 0; L < 16; ++L) {
        short8 seg;
        #pragma unroll
        for (int j = 0; j < 8; ++j) {
            float v = w[(size_t)k * DIM + (L & 7) * 8 + j];
            unsigned short h = f2bf(v);
            seg[j] = (L < 8) ? (short)h : (short)f2bf(v - bf2f(h));
        }
        *(short8*)(row + ((L ^ (k & 15)) << 3)) = seg;
    }
}

// ---------------------------------------------------------------------------
// Main: 512 blocks x 256 thr. Block = 128 latents x 1024 codes (8 chunks).
// Wave tile 64 lats x 64 codes; A-frags in regs; W double-buffered via
// global_load_lds (issued right after each barrier -> overlaps compute).
__global__ __launch_bounds__(256, 2)
void vq_main(const float* __restrict__ x, const float* __restrict__ w,
             const unsigned short* __restrict__ WEg, const float* __restrict__ wn,
             float* __restrict__ out, int* __restrict__ ctr, int* __restrict__ list) {
    __shared__ __align__(16) char smem[72192];
    unsigned short* XE = (unsigned short*)smem;        // [128][136] (phase 0 only)
    char* wbuf0 = smem + 34816;                        // 32 KB
    char* wbuf1 = smem;                                // 32 KB, aliases dead XE
    float* swn  = (float*)(smem + 67584);              // [1024]
    int*   bfin = (int*)(smem + 71680);                // [128]
    float* red_b1 = (float*)smem;                      // epilogue aliases
    int*   red_i1 = (int*)(smem + 16512);
    float* red_b2 = (float*)(smem + 33024);

    const int tid  = threadIdx.x;
    const int wave = tid >> 6, lane = tid & 63;
    const int r16  = lane & 15, quad = lane >> 4;
    const int LH = wave & 1, CH = wave >> 1;

    const int blk = blockIdx.x;
    const int b   = blk >> 3;
    const int hw0 = (blk & 7) * LPB;

    // Issue chunk0 DMA first (overlaps phase-0 conversion; disjoint LDS region)
    {
        const char* gsrc = (const char*)WEg + wave * 8192 + lane * 16;
        char* ldst = wbuf0 + wave * 8192;
        #pragma unroll
        for (int i = 0; i < 8; ++i) async_cp16(gsrc + i * 1024, ldst + i * 1024);
    }
    // Stage all code norms (4 KB, once)
    *(float4*)&swn[tid * 4] = *(const float4*)&wn[tid * 4];
    // Phase 0: convert x tile -> XE[lat][hi 0..63 | lo 64..127]
    {
        const int lat  = tid & 127;
        const int half = tid >> 7;
        const float* xb = x + (size_t)b * (DIM * HW) + hw0 + lat;
        #pragma unroll 8
        for (int c = 0; c < 32; ++c) {
            int chn = half * 32 + c;
            float v = xb[chn * HW];
            unsigned short h = f2bf(v);
            XE[lat * XROW + chn]      = h;
            XE[lat * XROW + 64 + chn] = f2bf(v - bf2f(h));
        }
    }
    __syncthreads();

    // A-frags: p0=hi k0-31, p1=hi k32-63, p2=lo k0-31, p3=lo k32-63
    short8 areg[4][4];
    #pragma unroll
    for (int lt = 0; lt < 4; ++lt)
        #pragma unroll
        for (int p = 0; p < 4; ++p)
            areg[lt][p] = *(const short8*)&XE[(LH * 64 + lt * 16 + r16) * XROW + p * 32 + quad * 8];

    float b1[16], b2[16]; int i1[16];
    #pragma unroll
    for (int sl = 0; sl < 16; ++sl) { b1[sl] = FLT_MAX; b2[sl] = FLT_MAX; i1[sl] = 0; }

    for (int ch = 0; ch < NCHUNK; ++ch) {
        __syncthreads();   // cur chunk DMA drained; prev buffer reads done
        if (ch + 1 < NCHUNK) {   // prefetch next chunk into the other buffer
            const char* gsrc = (const char*)WEg + (ch + 1) * 32768 + wave * 8192 + lane * 16;
            char* ldst = (((ch + 1) & 1) ? wbuf1 : wbuf0) + wave * 8192;
            #pragma unroll
            for (int i = 0; i < 8; ++i) async_cp16(gsrc + i * 1024, ldst + i * 1024);
        }
        const char* cbuf = (ch & 1) ? wbuf1 : wbuf0;

        f32x4 acc[4][4];
        #pragma unroll
        for (int lt = 0; lt < 4; ++lt)
            #pragma unroll
            for (int ct = 0; ct < 4; ++ct) acc[lt][ct] = (f32x4)0.f;

        // K=192: (X span, W span) pairs; spans: 0=hi0,1=hi1,2=lo0,3=lo1
        const int AI[6] = {0, 1, 0, 1, 2, 3};
        const int WS[6] = {0, 1, 2, 3, 0, 1};
        #pragma unroll
        for (int s = 0; s < 6; ++s) {
            short8 bf[4];
            #pragma unroll
            for (int ct = 0; ct < 4; ++ct) {
                int r = CH * 64 + ct * 16 + r16;
                int seg = (WS[s] * 4 + quad) ^ r16;    // matches prep swizzle
                bf[ct] = *(const short8*)(cbuf + r * 256 + seg * 16);
            }
            #pragma unroll
            for (int lt = 0; lt < 4; ++lt)
                #pragma unroll
                for (int ct = 0; ct < 4; ++ct)
                    acc[lt][ct] = __builtin_amdgcn_mfma_f32_16x16x32_bf16(
                        areg[lt][AI[s]], bf[ct], acc[lt][ct], 0, 0, 0);
        }

        #pragma unroll
        for (int ct = 0; ct < 4; ++ct) {
            float wnv = swn[ch * CPK + CH * 64 + ct * 16 + r16];
            int   kk  = ch * CPK + CH * 64 + ct * 16 + r16;
            #pragma unroll
            for (int lt = 0; lt < 4; ++lt)
                #pragma unroll
                for (int r = 0; r < 4; ++r) {
                    int sl = lt * 4 + r;
                    float sc = wnv - acc[lt][ct][r];
                    bool ltb = sc < b1[sl];
                    b2[sl] = fminf(b2[sl], fmaxf(sc, b1[sl]));  // loser of the duel
                    b1[sl] = ltb ? sc : b1[sl];
                    i1[sl] = ltb ? kk : i1[sl];
                }
        }
    }

    __syncthreads();   // W buffers dead; alias as reduction arrays
    {
        const int cid = CH * 16 + r16;
        #pragma unroll
        for (int lt = 0; lt < 4; ++lt)
            #pragma unroll
            for (int r = 0; r < 4; ++r) {
                int sl = lt * 4 + r;
                int lat = LH * 64 + lt * 16 + quad * 4 + r;
                red_b1[cid * 129 + lat] = b1[sl];
                red_i1[cid * 129 + lat] = i1[sl];
                red_b2[cid * 129 + lat] = b2[sl];
            }
    }
    __syncthreads();
    if (tid < LPB) {
        float B1 = red_b1[tid]; int I1 = red_i1[tid]; float B2 = red_b2[tid];
        #pragma unroll 4
        for (int cid = 1; cid < 32; ++cid) {
            float c1 = red_b1[cid * 129 + tid];
            int   ci = red_i1[cid * 129 + tid];
            float c2 = red_b2[cid * 129 + tid];
            if (c1 < B1 || (c1 == B1 && ci < I1)) { B2 = fminf(B1, c2); B1 = c1; I1 = ci; }
            else                                  { B2 = fminf(B2, c1); }
        }
        bfin[tid] = I1;
        if (B2 - B1 < EPS) {
            int pos = atomicAdd(ctr, 1);
            if (pos < RESCUE_CAP) list[pos] = blk * LPB + tid;
        }
    }
    __syncthreads();

    float* outp = out + (size_t)blk * (LPB * DIM);
    #pragma unroll
    for (int r = 0; r < 8; ++r) {
        int idx = r * 256 + tid;
        int row = idx >> 4, seg = idx & 15;
        int code = bfin[row];
        *(float4*)&outp[idx * 4] = *(const float4*)&w[(size_t)code * DIM + seg * 4];
    }
}

// ---------------------------------------------------------------------------
// Rescue: one WAVE per ambiguous latent, exact fp32 full-K rescore.
// 1024 blocks x 4 waves = 4096 slots (== RESCUE_CAP); no LDS, no barriers.
__global__ __launch_bounds__(256, 1)
void vq_rescue(const float* __restrict__ x, const float* __restrict__ w,
               const float* __restrict__ wn, float* __restrict__ out,
               const int* __restrict__ ctr, const int* __restrict__ list) {
    int cnt = ctr[0]; if (cnt > RESCUE_CAP) cnt = RESCUE_CAP;
    int g = blockIdx.x * 4 + (threadIdx.x >> 6);
    if (g >= cnt) return;
    const int lane = threadIdx.x & 63;
    const int n = list[g];
    const int b = n >> 10, hw = n & 1023;
    const float* xp = x + (size_t)b * (DIM * HW) + hw;
    float xs[DIM];
    #pragma unroll
    for (int d = 0; d < DIM; ++d) xs[d] = xp[d * HW];   // wave-uniform addresses
    float bb = FLT_MAX; int bi = 0;
    #pragma unroll 2
    for (int c = 0; c < 16; ++c) {
        int k = c * 64 + lane;
        const float4* wr = (const float4*)(w + (size_t)k * DIM);
        float a0 = 0.f, a1 = 0.f, a2 = 0.f, a3 = 0.f;
        #pragma unroll
        for (int j = 0; j < 16; ++j) {
            float4 v = wr[j];
            a0 += xs[4 * j]     * v.x;  a1 += xs[4 * j + 1] * v.y;
            a2 += xs[4 * j + 2] * v.z;  a3 += xs[4 * j + 3] * v.w;
        }
        float s = wn[k] - ((a0 + a1) + (a2 + a3));
        if (s < bb) { bb = s; bi = k; }
    }
    #pragma unroll
    for (int off = 32; off > 0; off >>= 1) {   // lex (score, k) wave argmin
        float ob = __shfl_down(bb, off);
        int   oi = __shfl_down(bi, off);
        if (ob < bb || (ob == bb && oi < bi)) { bb = ob; bi = oi; }
    }
    int kw = __shfl(bi, 0);
    out[(size_t)n * DIM + lane] = w[(size_t)kw * DIM + lane];
}

extern "C" void kernel_launch(void* const* d_in, const int* in_sizes, int n_in,
                              void* d_out, int out_size, void* d_ws, size_t ws_size,
                              hipStream_t stream) {
    const float* x = (const float*)d_in[0];
    const float* w = (const float*)d_in[1];
    float* out = (float*)d_out;
    unsigned short* WEg = (unsigned short*)d_ws;                  // 262144 B (swizzled)
    float* wn  = (float*)((char*)d_ws + 262144);                  // 4096 B
    int*   ctr = (int*)((char*)d_ws + 266240);                    // 16 B
    int*   list = (int*)((char*)d_ws + 266256);                   // 16384 B

    vq_prep<<<4, 256, 0, stream>>>(w, WEg, wn, ctr);
    vq_main<<<NLAT / LPB, 256, 0, stream>>>(x, w, WEg, wn, out, ctr, list);
    vq_rescue<<<RESCUE_CAP / 4, 256, 0, stream>>>(x, w, wn, out, ctr, list);
}